// Round 1
// baseline (628.711 us; speedup 1.0000x reference)
//
#include <hip/hip_runtime.h>
#include <math.h>

// Problem constants (from reference setup_inputs)
constexpr int   BSZ   = 16;
constexpr int   NDIM  = 128;
constexpr int   KP1   = 65537;      // K+1
constexpr long  NDATA = 500000;
constexpr float T_INV = 1.0f / 0.07f;
constexpr float MOM   = 0.5f;
constexpr float EPS   = 1e-12f;

// One 64-lane wave per (b,k) row: lane i loads float2 at row*128 + 2*i
// -> 512B fully-coalesced gather per row. Wave shuffle-reduce the dot.
__global__ __launch_bounds__(256) void logits_kernel(
        const float*  __restrict__ x,
        const int*    __restrict__ y,
        const int*    __restrict__ idx,
        const float*  __restrict__ memory,
        float*        __restrict__ logits) {
    const int wave = (blockIdx.x * blockDim.x + threadIdx.x) >> 6;
    const int lane = threadIdx.x & 63;
    const int R = BSZ * KP1;
    if (wave >= R) return;
    const int b = wave / KP1;
    const int k = wave - b * KP1;
    const int j = (k == 0) ? y[b] : idx[wave];

    const float2* __restrict__ mrow =
        (const float2*)(memory + (size_t)j * NDIM);
    const float2* __restrict__ xrow =
        (const float2*)(x + (size_t)b * NDIM);
    const float2 m  = mrow[lane];
    const float2 xv = xrow[lane];
    float s = m.x * xv.x + m.y * xv.y;
    #pragma unroll
    for (int off = 32; off > 0; off >>= 1)
        s += __shfl_down(s, off, 64);
    if (lane == 0) logits[wave] = s * T_INV;
}

// Streaming float4 copy: memory -> out_memory (256 MB each way).
__global__ __launch_bounds__(256) void copy_kernel(
        const float4* __restrict__ src,
        float4*       __restrict__ dst,
        int n4) {
    const int i = blockIdx.x * blockDim.x + threadIdx.x;
    if (i < n4) dst[i] = src[i];
}

// 16 blocks x 64 lanes: EMA-mix row y[b], normalize, scatter into out_mem.
// Runs AFTER copy_kernel (stream ordering) so it overwrites the stale copy.
__global__ __launch_bounds__(64) void update_kernel(
        const float* __restrict__ x,
        const int*   __restrict__ y,
        const float* __restrict__ memory,
        float*       __restrict__ labels,
        float*       __restrict__ out_mem) {
    const int b    = blockIdx.x;
    const int lane = threadIdx.x;
    const int yb   = y[b];
    const float2 m  = ((const float2*)(memory + (size_t)yb * NDIM))[lane];
    const float2 xv = ((const float2*)(x + (size_t)b * NDIM))[lane];
    float2 v;
    v.x = m.x * MOM + xv.x * (1.0f - MOM);
    v.y = m.y * MOM + xv.y * (1.0f - MOM);
    float s = v.x * v.x + v.y * v.y;
    #pragma unroll
    for (int off = 32; off > 0; off >>= 1)
        s += __shfl_xor(s, off, 64);          // butterfly: all lanes get sum
    const float n = fmaxf(sqrtf(s), EPS);
    float2 o; o.x = v.x / n; o.y = v.y / n;
    ((float2*)(out_mem + (size_t)yb * NDIM))[lane] = o;
    if (lane == 0) labels[b] = 0.0f;
}

extern "C" void kernel_launch(void* const* d_in, const int* in_sizes, int n_in,
                              void* d_out, int out_size, void* d_ws, size_t ws_size,
                              hipStream_t stream) {
    const float* x      = (const float*)d_in[0];
    const int*   y      = (const int*)  d_in[1];
    const int*   idx    = (const int*)  d_in[2];
    const float* memory = (const float*)d_in[3];

    float* logits  = (float*)d_out;                 // BSZ*KP1
    float* labels  = logits + (size_t)BSZ * KP1;    // BSZ
    float* out_mem = labels + BSZ;                  // NDATA*NDIM

    // 1) logits: one wave per row, 4 waves per 256-thread block
    const int R = BSZ * KP1;
    const int lblocks = (R + 3) / 4;
    logits_kernel<<<lblocks, 256, 0, stream>>>(x, y, idx, memory, logits);

    // 2) full memory copy (float4)
    const int n4 = (int)(NDATA * NDIM / 4);
    copy_kernel<<<(n4 + 255) / 256, 256, 0, stream>>>(
        (const float4*)memory, (float4*)out_mem, n4);

    // 3) EMA update of the 16 positive rows + zero labels
    update_kernel<<<BSZ, 64, 0, stream>>>(x, y, memory, labels, out_mem);
}